// Round 2
// baseline (451.418 us; speedup 1.0000x reference)
//
#include <hip/hip_runtime.h>

// DB4 analysis low-pass h and high-pass g[n] = (-1)^n h[7-n]
#define H0 0.2303778133088964f
#define H1 0.7148465705529155f
#define H2 0.6308807679298587f
#define H3 (-0.027983769416859854f)
#define H4 (-0.18703481171888114f)
#define H5 0.030841381835986965f
#define H6 0.032883011666982945f
#define H7 (-0.010597401785069032f)

// Tile: 32x32 output pixels per block.
// recon[m,n] depends on coeffs r,c in [(M-4)/2,(M+3)/2] x [(N-4)/2,(N+3)/2],
// which depend on x rows/cols [m-7, m+7]: halo 7 each side -> 46x46 x-tile.

__device__ __forceinline__ unsigned enc_f(float f) {
    unsigned b = __float_as_uint(f);
    return (b & 0x80000000u) ? ~b : (b | 0x80000000u);
}
__device__ __forceinline__ float dec_f(unsigned e) {
    unsigned b = (e & 0x80000000u) ? (e ^ 0x80000000u) : ~e;
    return __uint_as_float(b);
}

__global__ void init_mnmx_k(unsigned int* __restrict__ mnmx) {
    int t = threadIdx.x;
    if (t < 32) mnmx[t] = 0xFFFFFFFFu;       // running-min slots (encoded)
    else if (t < 64) mnmx[t] = 0u;           // running-max slots (encoded)
}

__global__ __launch_bounds__(256) void dwt_fused_k(const float* __restrict__ x,
                                                   float* __restrict__ out,
                                                   unsigned int* __restrict__ mnmx) {
    constexpr float h[8] = {H0, H1, H2, H3, H4, H5, H6, H7};
    constexpr float g[8] = {H7, -H6, H5, -H4, H3, -H2, H1, -H0};

    const int tileX = blockIdx.x;   // 0..15 -> N0
    const int tileY = blockIdx.y;   // 0..15 -> M0
    const int img   = blockIdx.z;   // 0..95 (b*3+c)
    const int M0 = tileY * 32, N0 = tileX * 32;
    const int tid = threadIdx.x;

    __shared__ float sx[46][48];    // x tile with 7-halo, padded cols
    __shared__ float uL[46][20];    // row-analysis (h along W), coeff cols
    __shared__ float uH[46][20];    // row-analysis (g along W)
    __shared__ float y1[20][20];    // band LH: h along H of uH
    __shared__ float y2[20][20];    // band HL: g along H of uL
    __shared__ float y3[20][20];    // band HH: g along H of uH
    __shared__ float sP[32][20];    // col-synth: h*y1 + g*y3  (gets g along W)
    __shared__ float sQ[32][20];    // col-synth: g*y2         (gets h along W)
    __shared__ float rmn[4], rmx[4];

    const float* xp = x + (size_t)img * (512 * 512);
    const int XR0 = M0 - 7, XC0 = N0 - 7;

    // Stage 1: load 46x46 x tile (zero-padded at image borders)
    for (int t = tid; t < 46 * 46; t += 256) {
        int rr = t / 46, cc = t - rr * 46;
        int gr = XR0 + rr, gc = XC0 + cc;
        float v = 0.f;
        if ((unsigned)gr < 512u && (unsigned)gc < 512u) v = xp[gr * 512 + gc];
        sx[rr][cc] = v;
    }
    __syncthreads();

    // Stage 2: row analysis. coeff col c = N0/2 - 2 + lc; x col local = 2*lc + j
    const int C0 = (N0 >> 1) - 2;
    for (int t = tid; t < 46 * 20; t += 256) {
        int p = t / 20, lc = t - p * 20;
        float aL = 0.f, aH = 0.f;
        if ((unsigned)(C0 + lc) < 256u) {
#pragma unroll
            for (int j = 0; j < 8; ++j) {
                float v = sx[p][2 * lc + j];
                aL += h[j] * v;
                aH += g[j] * v;
            }
        }
        uL[p][lc] = aL;
        uH[p][lc] = aH;
    }
    __syncthreads();

    // Stage 3: column analysis. coeff row r = M0/2 - 2 + lr; x row local = 2*lr + i
    const int R0 = (M0 >> 1) - 2;
    for (int t = tid; t < 20 * 20; t += 256) {
        int lr = t / 20, lc = t - lr * 20;
        float a1 = 0.f, a2 = 0.f, a3 = 0.f;
        if ((unsigned)(R0 + lr) < 256u) {
#pragma unroll
            for (int i = 0; i < 8; ++i) {
                float vH = uH[2 * lr + i][lc];
                float vL = uL[2 * lr + i][lc];
                a1 += h[i] * vH;
                a2 += g[i] * vL;
                a3 += g[i] * vH;
            }
        }
        y1[lr][lc] = a1;
        y2[lr][lc] = a2;
        y3[lr][lc] = a3;
    }
    __syncthreads();

    // Stage 4: column synthesis (upsample along H).
    // P[m][lc] = sum_k h[k]*y1[(m+k)/2][lc] + g[k]*y3[(m+k)/2][lc], (m+k) even
    // Q[m][lc] = sum_k g[k]*y2[(m+k)/2][lc]
    for (int t = tid; t < 32 * 20; t += 256) {
        int m = t / 20, lc = t - m * 20;
        int mh = (m + (m & 1)) >> 1;
        float p, q;
        if (m & 1) {
            p = h[1] * y1[mh][lc] + h[3] * y1[mh + 1][lc] + h[5] * y1[mh + 2][lc] + h[7] * y1[mh + 3][lc]
              + g[1] * y3[mh][lc] + g[3] * y3[mh + 1][lc] + g[5] * y3[mh + 2][lc] + g[7] * y3[mh + 3][lc];
            q = g[1] * y2[mh][lc] + g[3] * y2[mh + 1][lc] + g[5] * y2[mh + 2][lc] + g[7] * y2[mh + 3][lc];
        } else {
            p = h[0] * y1[mh][lc] + h[2] * y1[mh + 1][lc] + h[4] * y1[mh + 2][lc] + h[6] * y1[mh + 3][lc]
              + g[0] * y3[mh][lc] + g[2] * y3[mh + 1][lc] + g[4] * y3[mh + 2][lc] + g[6] * y3[mh + 3][lc];
            q = g[0] * y2[mh][lc] + g[2] * y2[mh + 1][lc] + g[4] * y2[mh + 2][lc] + g[6] * y2[mh + 3][lc];
        }
        sP[m][lc] = p;
        sQ[m][lc] = q;
    }
    __syncthreads();

    // Stage 5: row synthesis + store + local min/max
    float lmn = 3.4e38f, lmx = -3.4e38f;
    for (int t = tid; t < 32 * 32; t += 256) {
        int m = t >> 5, nl = t & 31;
        int nh = (nl + (nl & 1)) >> 1;
        float r;
        if (nl & 1) {
            r = g[1] * sP[m][nh] + g[3] * sP[m][nh + 1] + g[5] * sP[m][nh + 2] + g[7] * sP[m][nh + 3]
              + h[1] * sQ[m][nh] + h[3] * sQ[m][nh + 1] + h[5] * sQ[m][nh + 2] + h[7] * sQ[m][nh + 3];
        } else {
            r = g[0] * sP[m][nh] + g[2] * sP[m][nh + 1] + g[4] * sP[m][nh + 2] + g[6] * sP[m][nh + 3]
              + h[0] * sQ[m][nh] + h[2] * sQ[m][nh + 1] + h[4] * sQ[m][nh + 2] + h[6] * sQ[m][nh + 3];
        }
        out[((size_t)img * 512 + (M0 + m)) * 512 + (N0 + nl)] = r;
        lmn = fminf(lmn, r);
        lmx = fmaxf(lmx, r);
    }

    // block reduce min/max -> 2 atomics per block (per-sample slots)
#pragma unroll
    for (int off = 32; off > 0; off >>= 1) {
        lmn = fminf(lmn, __shfl_down(lmn, off));
        lmx = fmaxf(lmx, __shfl_down(lmx, off));
    }
    int wave = tid >> 6;
    if ((tid & 63) == 0) { rmn[wave] = lmn; rmx[wave] = lmx; }
    __syncthreads();
    if (tid == 0) {
        float mn = fminf(fminf(rmn[0], rmn[1]), fminf(rmn[2], rmn[3]));
        float mx = fmaxf(fmaxf(rmx[0], rmx[1]), fmaxf(rmx[2], rmx[3]));
        int b = img / 3;   // sample index
        atomicMin(&mnmx[b], enc_f(mn));
        atomicMax(&mnmx[32 + b], enc_f(mx));
    }
}

__global__ __launch_bounds__(256) void normalize_k(float* __restrict__ out,
                                                   const unsigned int* __restrict__ mnmx) {
    size_t i = (size_t)blockIdx.x * 256 + threadIdx.x;   // float4 index
    int s = (int)(i / 196608);                           // 786432/4 float4s per sample
    float mn = dec_f(mnmx[s]);
    float mx = dec_f(mnmx[32 + s]);
    float inv = 1.0f / (mx - mn + 1e-8f);
    float4 v = reinterpret_cast<float4*>(out)[i];
    v.x = (v.x - mn) * inv;
    v.y = (v.y - mn) * inv;
    v.z = (v.z - mn) * inv;
    v.w = (v.w - mn) * inv;
    reinterpret_cast<float4*>(out)[i] = v;
}

extern "C" void kernel_launch(void* const* d_in, const int* in_sizes, int n_in,
                              void* d_out, int out_size, void* d_ws, size_t ws_size,
                              hipStream_t stream) {
    const float* x = (const float*)d_in[0];
    float* out = (float*)d_out;
    unsigned int* mnmx = (unsigned int*)d_ws;

    hipLaunchKernelGGL(init_mnmx_k, dim3(1), dim3(64), 0, stream, mnmx);
    hipLaunchKernelGGL(dwt_fused_k, dim3(16, 16, 96), dim3(256), 0, stream, x, out, mnmx);
    // 32*3*512*512 / 4 floats per thread / 256 threads = 24576 blocks
    hipLaunchKernelGGL(normalize_k, dim3(24576), dim3(256), 0, stream, out, mnmx);
}

// Round 3
// 435.478 us; speedup vs baseline: 1.0366x; 1.0366x over previous
//
#include <hip/hip_runtime.h>

// DB4 analysis low-pass h; high-pass g[n] = (-1)^n h[7-n]
#define H0 0.2303778133088964f
#define H1 0.7148465705529155f
#define H2 0.6308807679298587f
#define H3 (-0.027983769416859854f)
#define H4 (-0.18703481171888114f)
#define H5 0.030841381835986965f
#define H6 0.032883011666982945f
#define H7 (-0.010597401785069032f)

__device__ __forceinline__ unsigned enc_f(float f) {
    unsigned b = __float_as_uint(f);
    return (b & 0x80000000u) ? ~b : (b | 0x80000000u);
}
__device__ __forceinline__ float dec_f(unsigned e) {
    unsigned b = (e & 0x80000000u) ? (e ^ 0x80000000u) : ~e;
    return __uint_as_float(b);
}

__global__ void init_mnmx_k(unsigned int* __restrict__ mnmx) {
    int t = threadIdx.x;
    if (t < 32) mnmx[t] = 0xFFFFFFFFu;       // running-min slots (encoded)
    else if (t < 64) mnmx[t] = 0u;           // running-max slots (encoded)
}

// LDS layout (bytes):
//   sx  [48][52] @ 0      (9984)   halo tile; reused by sP/sQ after stage 3
//   sP  [32][20] @ 0      (2560)
//   sQ  [32][20] @ 2560   (2560)
//   uL  [48][20] @ 9984   (3840)
//   uH  [48][20] @ 13824  (3840)
//   y1  [20][20] @ 17664  (1600)
//   y2  [20][20] @ 19264  (1600)
//   y3  [20][20] @ 20864  (1600)
//   red [8]      @ 22464  (32)     -> total 22496 B -> 7 blocks/CU
__global__ __launch_bounds__(256, 7) void dwt_fused_k(const float* __restrict__ x,
                                                      float* __restrict__ out,
                                                      unsigned int* __restrict__ mnmx) {
    constexpr float h[8] = {H0, H1, H2, H3, H4, H5, H6, H7};
    constexpr float g[8] = {H7, -H6, H5, -H4, H3, -H2, H1, -H0};

    const int N0 = blockIdx.x * 32;
    const int M0 = blockIdx.y * 32;
    const int img = blockIdx.z;          // b*3 + c
    const int tid = threadIdx.x;

    __shared__ __align__(16) unsigned char smem[22496];
    float* sx = (float*)smem;                    // [48][52]
    float* sP = (float*)smem;                    // [32][20]
    float* sQ = (float*)(smem + 2560);           // [32][20]
    float* uL = (float*)(smem + 9984);           // [48][20]
    float* uH = (float*)(smem + 13824);          // [48][20]
    float* y1 = (float*)(smem + 17664);          // [20][20]
    float* y2 = (float*)(smem + 19264);          // [20][20]
    float* y3 = (float*)(smem + 20864);          // [20][20]
    float* red = (float*)(smem + 22464);         // rmn[4], rmx[4]

    const float* xp = x + (size_t)img * (512 * 512);

    // ---- Stage 1: load 48x48 halo tile (base M0-8, N0-8) as aligned float4 ----
    {
        const int gr0 = M0 - 8, gc0 = N0 - 8;
        for (int k = tid; k < 576; k += 256) {       // 48 rows x 12 float4
            int row = k / 12;
            int c4 = k - row * 12;
            int gr = gr0 + row;
            int gc = gc0 + 4 * c4;
            float4 v = make_float4(0.f, 0.f, 0.f, 0.f);
            if ((unsigned)gr < 512u && (unsigned)gc < 512u)
                v = *(const float4*)(xp + gr * 512 + gc);
            *(float4*)(sx + row * 52 + 4 * c4) = v;
        }
    }
    __syncthreads();

    // ---- Stage 2: row analysis. coeff col c = C0 + lc; x local col = 1 + 2*lc + j ----
    const int C0 = (N0 >> 1) - 2;
    if (tid < 230) {                                 // 46 rows x 5 col-groups
        int p = tid / 5;                             // 0..45
        int q = tid - p * 5;                         // 0..4, lc = 4q+d
        int pr = p + 1;                              // sx row 1..46
        const float4* wr = (const float4*)(sx + pr * 52 + 8 * q);
        float4 w0 = wr[0], w1 = wr[1], w2 = wr[2], w3 = wr[3];
        float W[16] = {w0.x, w0.y, w0.z, w0.w, w1.x, w1.y, w1.z, w1.w,
                       w2.x, w2.y, w2.z, w2.w, w3.x, w3.y, w3.z, w3.w};
        float aL[4] = {0.f, 0.f, 0.f, 0.f}, aH[4] = {0.f, 0.f, 0.f, 0.f};
#pragma unroll
        for (int d = 0; d < 4; ++d) {
#pragma unroll
            for (int j = 0; j < 8; ++j) {
                float v = W[1 + 2 * d + j];
                aL[d] += h[j] * v;
                aH[d] += g[j] * v;
            }
            if ((unsigned)(C0 + 4 * q + d) >= 256u) { aL[d] = 0.f; aH[d] = 0.f; }
        }
        *(float4*)(uL + pr * 20 + 4 * q) = make_float4(aL[0], aL[1], aL[2], aL[3]);
        *(float4*)(uH + pr * 20 + 4 * q) = make_float4(aH[0], aH[1], aH[2], aH[3]);
    }
    __syncthreads();

    // ---- Stage 3: column analysis. coeff row r = R0 + lr; u row = 1 + 2*lr + i ----
    const int R0 = (M0 >> 1) - 2;
    if (tid < 100) {                                 // 20 rows x 5 col-groups
        int lr = tid / 5;
        int q = tid - lr * 5;
        float a1[4] = {0.f, 0.f, 0.f, 0.f};
        float a2[4] = {0.f, 0.f, 0.f, 0.f};
        float a3[4] = {0.f, 0.f, 0.f, 0.f};
        if ((unsigned)(R0 + lr) < 256u) {
#pragma unroll
            for (int i = 0; i < 8; ++i) {
                float4 vH = *(const float4*)(uH + (1 + 2 * lr + i) * 20 + 4 * q);
                float4 vL = *(const float4*)(uL + (1 + 2 * lr + i) * 20 + 4 * q);
                a1[0] += h[i] * vH.x; a1[1] += h[i] * vH.y; a1[2] += h[i] * vH.z; a1[3] += h[i] * vH.w;
                a2[0] += g[i] * vL.x; a2[1] += g[i] * vL.y; a2[2] += g[i] * vL.z; a2[3] += g[i] * vL.w;
                a3[0] += g[i] * vH.x; a3[1] += g[i] * vH.y; a3[2] += g[i] * vH.z; a3[3] += g[i] * vH.w;
            }
        }
        *(float4*)(y1 + lr * 20 + 4 * q) = make_float4(a1[0], a1[1], a1[2], a1[3]);
        *(float4*)(y2 + lr * 20 + 4 * q) = make_float4(a2[0], a2[1], a2[2], a2[3]);
        *(float4*)(y3 + lr * 20 + 4 * q) = make_float4(a3[0], a3[1], a3[2], a3[3]);
    }
    __syncthreads();

    // ---- Stage 4: column synthesis -> sP, sQ (overwrites dead sx region) ----
    if (tid < 160) {                                 // 32 rows x 5 col-groups
        int m = tid / 5;
        int q = tid - m * 5;
        int mh = (m + (m & 1)) >> 1;
        int t0 = m & 1;
        // parity-selected taps (compile-time constants behind cndmask)
        float ch0 = t0 ? H1 : H0, ch1 = t0 ? H3 : H2, ch2 = t0 ? H5 : H4, ch3 = t0 ? H7 : H6;
        float cg0 = t0 ? -H6 : H7, cg1 = t0 ? -H4 : H5, cg2 = t0 ? -H2 : H3, cg3 = t0 ? -H0 : H1;
        float P[4] = {0.f, 0.f, 0.f, 0.f}, Q[4] = {0.f, 0.f, 0.f, 0.f};
#pragma unroll
        for (int k = 0; k < 4; ++k) {
            float chk = (k == 0) ? ch0 : (k == 1) ? ch1 : (k == 2) ? ch2 : ch3;
            float cgk = (k == 0) ? cg0 : (k == 1) ? cg1 : (k == 2) ? cg2 : cg3;
            float4 v1 = *(const float4*)(y1 + (mh + k) * 20 + 4 * q);
            float4 v3 = *(const float4*)(y3 + (mh + k) * 20 + 4 * q);
            float4 v2 = *(const float4*)(y2 + (mh + k) * 20 + 4 * q);
            P[0] += chk * v1.x + cgk * v3.x; P[1] += chk * v1.y + cgk * v3.y;
            P[2] += chk * v1.z + cgk * v3.z; P[3] += chk * v1.w + cgk * v3.w;
            Q[0] += cgk * v2.x; Q[1] += cgk * v2.y; Q[2] += cgk * v2.z; Q[3] += cgk * v2.w;
        }
        *(float4*)(sP + m * 20 + 4 * q) = make_float4(P[0], P[1], P[2], P[3]);
        *(float4*)(sQ + m * 20 + 4 * q) = make_float4(Q[0], Q[1], Q[2], Q[3]);
    }
    __syncthreads();

    // ---- Stage 5: row synthesis, 8 outputs/thread, float4 stores + min/max ----
    float lmn = 3.4e38f, lmx = -3.4e38f;
    if (tid < 128) {                                 // 32 rows x 4 groups of 8 cols
        int m = tid >> 2;
        int qq = tid & 3;                            // nl = 8*qq + e
        const float* pp = sP + m * 20 + 4 * qq;
        const float* qp = sQ + m * 20 + 4 * qq;
        float4 pa = *(const float4*)pp, pb = *(const float4*)(pp + 4);
        float4 qa = *(const float4*)qp, qb = *(const float4*)(qp + 4);
        float sp[8] = {pa.x, pa.y, pa.z, pa.w, pb.x, pb.y, pb.z, pb.w};
        float sq[8] = {qa.x, qa.y, qa.z, qa.w, qb.x, qb.y, qb.z, qb.w};
        float val[8];
#pragma unroll
        for (int e = 0; e < 8; ++e) {
            const int t0 = e & 1;
            const int r0 = (e + (e & 1)) >> 1;       // nh - 4*qq
            float r = g[t0] * sp[r0] + g[t0 + 2] * sp[r0 + 1] + g[t0 + 4] * sp[r0 + 2] + g[t0 + 6] * sp[r0 + 3]
                    + h[t0] * sq[r0] + h[t0 + 2] * sq[r0 + 1] + h[t0 + 4] * sq[r0 + 2] + h[t0 + 6] * sq[r0 + 3];
            val[e] = r;
            lmn = fminf(lmn, r);
            lmx = fmaxf(lmx, r);
        }
        float* op = out + ((size_t)img * 512 + (M0 + m)) * 512 + (N0 + 8 * qq);
        *(float4*)op = make_float4(val[0], val[1], val[2], val[3]);
        *(float4*)(op + 4) = make_float4(val[4], val[5], val[6], val[7]);
    }

    // block reduce min/max -> 2 atomics per block
#pragma unroll
    for (int off = 32; off > 0; off >>= 1) {
        lmn = fminf(lmn, __shfl_down(lmn, off));
        lmx = fmaxf(lmx, __shfl_down(lmx, off));
    }
    int wv = tid >> 6;
    if ((tid & 63) == 0) { red[wv] = lmn; red[4 + wv] = lmx; }
    __syncthreads();
    if (tid == 0) {
        float mn = fminf(fminf(red[0], red[1]), fminf(red[2], red[3]));
        float mx = fmaxf(fmaxf(red[4], red[5]), fmaxf(red[6], red[7]));
        int b = img / 3;
        atomicMin(&mnmx[b], enc_f(mn));
        atomicMax(&mnmx[32 + b], enc_f(mx));
    }
}

__global__ __launch_bounds__(256) void normalize_k(float* __restrict__ out,
                                                   const unsigned int* __restrict__ mnmx) {
    int t = blockIdx.x * 256 + threadIdx.x;          // 4096*256 = 1048576 threads
    float4* o4 = (float4*)out;
#pragma unroll
    for (int it = 0; it < 6; ++it) {                 // 6291456 float4 total, exact cover
        size_t i = (size_t)t + (size_t)it * 1048576;
        int s = (int)(i / 196608);                   // float4s per sample
        float mn = dec_f(mnmx[s]);
        float mx = dec_f(mnmx[32 + s]);
        float inv = 1.0f / (mx - mn + 1e-8f);
        float4 v = o4[i];
        v.x = (v.x - mn) * inv;
        v.y = (v.y - mn) * inv;
        v.z = (v.z - mn) * inv;
        v.w = (v.w - mn) * inv;
        o4[i] = v;
    }
}

extern "C" void kernel_launch(void* const* d_in, const int* in_sizes, int n_in,
                              void* d_out, int out_size, void* d_ws, size_t ws_size,
                              hipStream_t stream) {
    const float* x = (const float*)d_in[0];
    float* out = (float*)d_out;
    unsigned int* mnmx = (unsigned int*)d_ws;

    hipLaunchKernelGGL(init_mnmx_k, dim3(1), dim3(64), 0, stream, mnmx);
    hipLaunchKernelGGL(dwt_fused_k, dim3(16, 16, 96), dim3(256), 0, stream, x, out, mnmx);
    hipLaunchKernelGGL(normalize_k, dim3(4096), dim3(256), 0, stream, out, mnmx);
}

// Round 7
// 241.139 us; speedup vs baseline: 1.8720x; 1.8059x over previous
//
#include <hip/hip_runtime.h>

// DB4 analysis low-pass h; high-pass g[n] = (-1)^n h[7-n]
#define H0 0.2303778133088964f
#define H1 0.7148465705529155f
#define H2 0.6308807679298587f
#define H3 (-0.027983769416859854f)
#define H4 (-0.18703481171888114f)
#define H5 0.030841381835986965f
#define H6 0.032883011666982945f
#define H7 (-0.010597401785069032f)

// Workspace layout (floats):
//   [0, 24576)        per-block partial min
//   [24576, 49152)    per-block partial max
//   [49152, 49184)    per-sample min (32)
//   [49184, 49216)    per-sample max (32)

// LDS layout (bytes), lifetime-overlapped:
//   region A @0     : sx[46][52] (9568)  stages 1-2
//                     then y1@0(1600) y2@1600 y3@3200, red@4800  stages 3-4
//   region B @9568  : uL[46][20](3680) uH@13248(3680)            stages 2-3
//                     then sP@9568(2560) sQ@12128(2560)          stages 4-5
//   total 16928 B -> LDS allows 9 blocks/CU; wave cap 8 blocks/CU.
__global__ __launch_bounds__(256, 8) void dwt_fused_k(const float* __restrict__ x,
                                                      float* __restrict__ out,
                                                      float* __restrict__ pmn,
                                                      float* __restrict__ pmx) {
    constexpr float h[8] = {H0, H1, H2, H3, H4, H5, H6, H7};
    constexpr float g[8] = {H7, -H6, H5, -H4, H3, -H2, H1, -H0};

    const int tileX = blockIdx.x;
    const int tileY = blockIdx.y;
    const int img = blockIdx.z;          // b*3 + c
    const int N0 = tileX * 32;
    const int M0 = tileY * 32;
    const int tid = threadIdx.x;

    __shared__ __align__(16) unsigned char smem[16928];
    float* sx = (float*)smem;                    // [46][52]
    float* y1 = (float*)smem;                    // [20][20]
    float* y2 = (float*)(smem + 1600);           // [20][20]
    float* y3 = (float*)(smem + 3200);           // [20][20]
    float* red = (float*)(smem + 4800);          // [8]
    float* uL = (float*)(smem + 9568);           // [46][20]
    float* uH = (float*)(smem + 13248);          // [46][20]
    float* sP = (float*)(smem + 9568);           // [32][20]
    float* sQ = (float*)(smem + 12128);          // [32][20]

    const float* xp = x + (size_t)img * (512 * 512);

    // ---- Stage 1: load 46x52 halo tile (base M0-7, N0-8), aligned float4 ----
    {
        const int gr0 = M0 - 7, gc0 = N0 - 8;
        for (int k = tid; k < 598; k += 256) {       // 46 rows x 13 float4
            int row = k / 13;
            int c4 = k - row * 13;
            int gr = gr0 + row;
            int gc = gc0 + 4 * c4;
            float4 v = make_float4(0.f, 0.f, 0.f, 0.f);
            if ((unsigned)gr < 512u && (unsigned)gc < 512u)
                v = *(const float4*)(xp + gr * 512 + gc);
            *(float4*)(sx + row * 52 + 4 * c4) = v;
        }
    }
    __syncthreads();

    // ---- Stage 2: row analysis. coeff col c = C0+lc, lc=4q+d; W covers local cols 8q..8q+15 ----
    const int C0 = (N0 >> 1) - 2;
    if (tid < 230) {                                 // 46 rows x 5 col-groups
        int p = tid / 5;
        int q = tid - p * 5;
        const float4* wr = (const float4*)(sx + p * 52 + 8 * q);
        float4 w0 = wr[0], w1 = wr[1], w2 = wr[2], w3 = wr[3];
        float W[16] = {w0.x, w0.y, w0.z, w0.w, w1.x, w1.y, w1.z, w1.w,
                       w2.x, w2.y, w2.z, w2.w, w3.x, w3.y, w3.z, w3.w};
        float aL[4] = {0.f, 0.f, 0.f, 0.f}, aH[4] = {0.f, 0.f, 0.f, 0.f};
#pragma unroll
        for (int d = 0; d < 4; ++d) {
#pragma unroll
            for (int j = 0; j < 8; ++j) {
                float v = W[1 + 2 * d + j];
                aL[d] += h[j] * v;
                aH[d] += g[j] * v;
            }
            if ((unsigned)(C0 + 4 * q + d) >= 256u) { aL[d] = 0.f; aH[d] = 0.f; }
        }
        *(float4*)(uL + p * 20 + 4 * q) = make_float4(aL[0], aL[1], aL[2], aL[3]);
        *(float4*)(uH + p * 20 + 4 * q) = make_float4(aH[0], aH[1], aH[2], aH[3]);
    }
    __syncthreads();

    // ---- Stage 3: column analysis. coeff row r = R0+lr; u rows 2lr..2lr+7 ----
    const int R0 = (M0 >> 1) - 2;
    if (tid < 100) {                                 // 20 rows x 5 col-groups
        int lr = tid / 5;
        int q = tid - lr * 5;
        float a1[4] = {0.f, 0.f, 0.f, 0.f};
        float a2[4] = {0.f, 0.f, 0.f, 0.f};
        float a3[4] = {0.f, 0.f, 0.f, 0.f};
        if ((unsigned)(R0 + lr) < 256u) {
#pragma unroll
            for (int i = 0; i < 8; ++i) {
                float4 vH = *(const float4*)(uH + (2 * lr + i) * 20 + 4 * q);
                float4 vL = *(const float4*)(uL + (2 * lr + i) * 20 + 4 * q);
                a1[0] += h[i] * vH.x; a1[1] += h[i] * vH.y; a1[2] += h[i] * vH.z; a1[3] += h[i] * vH.w;
                a2[0] += g[i] * vL.x; a2[1] += g[i] * vL.y; a2[2] += g[i] * vL.z; a2[3] += g[i] * vL.w;
                a3[0] += g[i] * vH.x; a3[1] += g[i] * vH.y; a3[2] += g[i] * vH.z; a3[3] += g[i] * vH.w;
            }
        }
        *(float4*)(y1 + lr * 20 + 4 * q) = make_float4(a1[0], a1[1], a1[2], a1[3]);
        *(float4*)(y2 + lr * 20 + 4 * q) = make_float4(a2[0], a2[1], a2[2], a2[3]);
        *(float4*)(y3 + lr * 20 + 4 * q) = make_float4(a3[0], a3[1], a3[2], a3[3]);
    }
    __syncthreads();

    // ---- Stage 4: column synthesis -> sP, sQ (into dead uL/uH region) ----
    if (tid < 160) {                                 // 32 rows x 5 col-groups
        int m = tid / 5;
        int q = tid - m * 5;
        int mh = (m + (m & 1)) >> 1;
        int t0 = m & 1;
        float ch0 = t0 ? H1 : H0, ch1 = t0 ? H3 : H2, ch2 = t0 ? H5 : H4, ch3 = t0 ? H7 : H6;
        float cg0 = t0 ? -H6 : H7, cg1 = t0 ? -H4 : H5, cg2 = t0 ? -H2 : H3, cg3 = t0 ? -H0 : H1;
        float P[4] = {0.f, 0.f, 0.f, 0.f}, Q[4] = {0.f, 0.f, 0.f, 0.f};
#pragma unroll
        for (int k = 0; k < 4; ++k) {
            float chk = (k == 0) ? ch0 : (k == 1) ? ch1 : (k == 2) ? ch2 : ch3;
            float cgk = (k == 0) ? cg0 : (k == 1) ? cg1 : (k == 2) ? cg2 : cg3;
            float4 v1 = *(const float4*)(y1 + (mh + k) * 20 + 4 * q);
            float4 v3 = *(const float4*)(y3 + (mh + k) * 20 + 4 * q);
            float4 v2 = *(const float4*)(y2 + (mh + k) * 20 + 4 * q);
            P[0] += chk * v1.x + cgk * v3.x; P[1] += chk * v1.y + cgk * v3.y;
            P[2] += chk * v1.z + cgk * v3.z; P[3] += chk * v1.w + cgk * v3.w;
            Q[0] += cgk * v2.x; Q[1] += cgk * v2.y; Q[2] += cgk * v2.z; Q[3] += cgk * v2.w;
        }
        *(float4*)(sP + m * 20 + 4 * q) = make_float4(P[0], P[1], P[2], P[3]);
        *(float4*)(sQ + m * 20 + 4 * q) = make_float4(Q[0], Q[1], Q[2], Q[3]);
    }
    __syncthreads();

    // ---- Stage 5: row synthesis, 8 outputs/thread, float4 stores + min/max ----
    float lmn = 3.4e38f, lmx = -3.4e38f;
    if (tid < 128) {                                 // 32 rows x 4 groups of 8 cols
        int m = tid >> 2;
        int qq = tid & 3;
        const float* pp = sP + m * 20 + 4 * qq;
        const float* qp = sQ + m * 20 + 4 * qq;
        float4 pa = *(const float4*)pp, pb = *(const float4*)(pp + 4);
        float4 qa = *(const float4*)qp, qb = *(const float4*)(qp + 4);
        float sp[8] = {pa.x, pa.y, pa.z, pa.w, pb.x, pb.y, pb.z, pb.w};
        float sq[8] = {qa.x, qa.y, qa.z, qa.w, qb.x, qb.y, qb.z, qb.w};
        float val[8];
#pragma unroll
        for (int e = 0; e < 8; ++e) {
            const int t0 = e & 1;
            const int r0 = (e + (e & 1)) >> 1;
            float r = g[t0] * sp[r0] + g[t0 + 2] * sp[r0 + 1] + g[t0 + 4] * sp[r0 + 2] + g[t0 + 6] * sp[r0 + 3]
                    + h[t0] * sq[r0] + h[t0 + 2] * sq[r0 + 1] + h[t0 + 4] * sq[r0 + 2] + h[t0 + 6] * sq[r0 + 3];
            val[e] = r;
            lmn = fminf(lmn, r);
            lmx = fmaxf(lmx, r);
        }
        float* op = out + ((size_t)img * 512 + (M0 + m)) * 512 + (N0 + 8 * qq);
        *(float4*)op = make_float4(val[0], val[1], val[2], val[3]);
        *(float4*)(op + 4) = make_float4(val[4], val[5], val[6], val[7]);
    }

    // block reduce -> ONE partial pair per block, distinct address (no atomics)
#pragma unroll
    for (int off = 32; off > 0; off >>= 1) {
        lmn = fminf(lmn, __shfl_down(lmn, off));
        lmx = fmaxf(lmx, __shfl_down(lmx, off));
    }
    int wv = tid >> 6;
    if ((tid & 63) == 0) { red[wv] = lmn; red[4 + wv] = lmx; }
    __syncthreads();
    if (tid == 0) {
        float mn = fminf(fminf(red[0], red[1]), fminf(red[2], red[3]));
        float mx = fmaxf(fmaxf(red[4], red[5]), fmaxf(red[6], red[7]));
        int blin = (img * 16 + tileY) * 16 + tileX;
        pmn[blin] = mn;
        pmx[blin] = mx;
    }
}

// 32 blocks (one per sample): fold 768 partials -> mn[32], mx[32]
__global__ __launch_bounds__(256) void minmax_reduce_k(const float* __restrict__ pmn,
                                                       const float* __restrict__ pmx,
                                                       float* __restrict__ mnmx) {
    __shared__ float r[8];
    int s = blockIdx.x;
    int tid = threadIdx.x;
    int base = s * 768;
    float lmn = 3.4e38f, lmx = -3.4e38f;
#pragma unroll
    for (int k = 0; k < 3; ++k) {
        lmn = fminf(lmn, pmn[base + tid + 256 * k]);
        lmx = fmaxf(lmx, pmx[base + tid + 256 * k]);
    }
#pragma unroll
    for (int off = 32; off > 0; off >>= 1) {
        lmn = fminf(lmn, __shfl_down(lmn, off));
        lmx = fmaxf(lmx, __shfl_down(lmx, off));
    }
    int wv = tid >> 6;
    if ((tid & 63) == 0) { r[wv] = lmn; r[4 + wv] = lmx; }
    __syncthreads();
    if (tid == 0) {
        mnmx[s]      = fminf(fminf(r[0], r[1]), fminf(r[2], r[3]));
        mnmx[32 + s] = fmaxf(fmaxf(r[4], r[5]), fmaxf(r[6], r[7]));
    }
}

__global__ __launch_bounds__(256) void normalize_k(float* __restrict__ out,
                                                   const float* __restrict__ mnmx) {
    int t = blockIdx.x * 256 + threadIdx.x;          // 4096*256 = 1048576 threads
    float4* o4 = (float4*)out;
#pragma unroll
    for (int it = 0; it < 6; ++it) {                 // 6291456 float4 total, exact cover
        size_t i = (size_t)t + (size_t)it * 1048576;
        int s = (int)(i / 196608);                   // float4s per sample
        float mn = mnmx[s];
        float mx = mnmx[32 + s];
        float inv = 1.0f / (mx - mn + 1e-8f);
        float4 v = o4[i];
        v.x = (v.x - mn) * inv;
        v.y = (v.y - mn) * inv;
        v.z = (v.z - mn) * inv;
        v.w = (v.w - mn) * inv;
        o4[i] = v;
    }
}

extern "C" void kernel_launch(void* const* d_in, const int* in_sizes, int n_in,
                              void* d_out, int out_size, void* d_ws, size_t ws_size,
                              hipStream_t stream) {
    const float* x = (const float*)d_in[0];
    float* out = (float*)d_out;
    float* wsf = (float*)d_ws;
    float* pmn = wsf;                 // 24576
    float* pmx = wsf + 24576;         // 24576
    float* mnmx = wsf + 49152;        // 64

    hipLaunchKernelGGL(dwt_fused_k, dim3(16, 16, 96), dim3(256), 0, stream, x, out, pmn, pmx);
    hipLaunchKernelGGL(minmax_reduce_k, dim3(32), dim3(256), 0, stream, pmn, pmx, mnmx);
    hipLaunchKernelGGL(normalize_k, dim3(4096), dim3(256), 0, stream, out, mnmx);
}